// Round 3
// baseline (1273.267 us; speedup 1.0000x reference)
//
#include <hip/hip_runtime.h>

typedef unsigned int u32;
typedef unsigned short u16;
typedef __attribute__((ext_vector_type(8))) short bf16x8;
typedef __attribute__((ext_vector_type(4))) float f32x4;

#define DEVI static __device__ __forceinline__

DEVI u16 f2bf(float f) {
    u32 u = __float_as_uint(f);
    u32 r = u + 0x7FFFu + ((u >> 16) & 1u);   // RNE (inputs finite)
    return (u16)(r >> 16);
}
DEVI float bf2f(u16 s) { return __uint_as_float(((u32)s) << 16); }
DEVI void split2(float a, u16& h, u16& l) {   // a ≈ hi + lo, residual ≤ 2^-18|a|
    h = f2bf(a);
    l = f2bf(a - bf2f(h));
}

union U4 { uint4 v; u16 s[8]; };

// ---------------------------------------------------------------- f32 -> (hi,lo) bf16 planes
__global__ __launch_bounds__(256) void convert_split_kernel(const float* __restrict__ in,
                                                            u16* __restrict__ hi,
                                                            u16* __restrict__ lo, int n) {
    int i = blockIdx.x * 256 + threadIdx.x;
    if (i < n) { u16 h, l; split2(in[i], h, l); hi[i] = h; lo[i] = l; }
}

// ---------------------------------------------------------------- proxy-side K/V (tiny, fp32 VALU)
struct KVArgs {
    const float *proxy;
    const float *ow1, *og1, *ob1, *om1, *ov1;
    const float *ow2, *og2, *ob2, *om2, *ov2;
    const float *dw,  *dg,  *db,  *dm,  *dv;
    float *kmat;   // [B][256][19]
    float *vmat;   // [B][19][256]
};
__global__ __launch_bounds__(256) void kv_kernel(KVArgs a) {
    __shared__ float pl[512 * 19];
    __shared__ float t1[256 * 19];
    const int t = threadIdx.x;
    const int b = blockIdx.x;
    const float* pb = a.proxy + (size_t)b * 512 * 19;
    for (int i = t; i < 512 * 19; i += 256) pl[i] = pb[i];
    __syncthreads();
    const int o = t;
    {
        float acc[19] = {0.f};
        const float* wr = a.ow1 + (size_t)o * 512;
        for (int c = 0; c < 512; ++c) {
            float wv = wr[c];
#pragma unroll
            for (int kk = 0; kk < 19; ++kk) acc[kk] += wv * pl[c * 19 + kk];
        }
        float sc = a.og1[o] * __frsqrt_rn(a.ov1[o] + 1e-5f);
        float sh = a.ob1[o] - a.om1[o] * sc;
#pragma unroll
        for (int kk = 0; kk < 19; ++kk) t1[o * 19 + kk] = fmaxf(acc[kk] * sc + sh, 0.f);
    }
    __syncthreads();
    {
        float acc[19] = {0.f};
        const float* wr = a.ow2 + (size_t)o * 256;
        for (int c = 0; c < 256; ++c) {
            float wv = wr[c];
#pragma unroll
            for (int kk = 0; kk < 19; ++kk) acc[kk] += wv * t1[c * 19 + kk];
        }
        float sc = a.og2[o] * __frsqrt_rn(a.ov2[o] + 1e-5f);
        float sh = a.ob2[o] - a.om2[o] * sc;
#pragma unroll
        for (int kk = 0; kk < 19; ++kk)
            a.kmat[((size_t)b * 256 + o) * 19 + kk] = fmaxf(acc[kk] * sc + sh, 0.f);
    }
    {
        float acc[19] = {0.f};
        const float* wr = a.dw + (size_t)o * 512;
        for (int c = 0; c < 512; ++c) {
            float wv = wr[c];
#pragma unroll
            for (int kk = 0; kk < 19; ++kk) acc[kk] += wv * pl[c * 19 + kk];
        }
        float sc = a.dg[o] * __frsqrt_rn(a.dv[o] + 1e-5f);
        float sh = a.db[o] - a.dm[o] * sc;
#pragma unroll
        for (int kk = 0; kk < 19; ++kk)
            a.vmat[((size_t)b * 19 + kk) * 256 + o] = fmaxf(acc[kk] * sc + sh, 0.f);
    }
}

// ---------------------------------------------------------------- attention: fp32 q, fp32 softmax, split-bf16 ctx out
struct AttnArgs { const float* q2f; const float* kmat; const float* vmat;
                  u16* ctxh; u16* ctxl; long long p_off; };
__global__ __launch_bounds__(256) void attn_kernel(AttnArgs a) {
    __shared__ float kl[256 * 19];   // [c][kk]
    __shared__ float vl[19 * 256];   // [kk][c]
    const int t = threadIdx.x;
    const size_t pl_ = (size_t)blockIdx.x * 256;        // pass-local pixel base
    const size_t pg  = (size_t)a.p_off + pl_;           // global pixel base
    const int b = (int)(pg >> 14);
    for (int i = t; i < 256 * 19; i += 256) kl[i] = a.kmat[(size_t)b * 256 * 19 + i];
    for (int i = t; i < 19 * 256; i += 256) vl[i] = a.vmat[(size_t)b * 19 * 256 + i];
    __syncthreads();
    const float* qrow = a.q2f + (pl_ + t) * 256;
    float sim[19] = {0.f};
    for (int j = 0; j < 64; ++j) {
        float4 qv = reinterpret_cast<const float4*>(qrow)[j];
#pragma unroll
        for (int e = 0; e < 4; ++e) {
            float qf = (e == 0) ? qv.x : (e == 1) ? qv.y : (e == 2) ? qv.z : qv.w;
            int c = j * 4 + e;
#pragma unroll
            for (int kk = 0; kk < 19; ++kk) sim[kk] += qf * kl[c * 19 + kk];  // broadcast, no conflict
        }
    }
    float mx = -1e30f;
#pragma unroll
    for (int kk = 0; kk < 19; ++kk) { sim[kk] *= 0.0625f; mx = fmaxf(mx, sim[kk]); }
    float ssum = 0.f;
#pragma unroll
    for (int kk = 0; kk < 19; ++kk) { sim[kk] = __expf(sim[kk] - mx); ssum += sim[kk]; }
    const float inv = 1.f / ssum;
#pragma unroll
    for (int kk = 0; kk < 19; ++kk) sim[kk] *= inv;
    u16* crh = a.ctxh + (pg + t) * 256;
    u16* crl = a.ctxl + (pg + t) * 256;
    for (int j = 0; j < 32; ++j) {
        U4 hh, ll;
#pragma unroll
        for (int e = 0; e < 8; ++e) {
            int c = j * 8 + e;
            float acc = 0.f;
#pragma unroll
            for (int kk = 0; kk < 19; ++kk) acc += sim[kk] * vl[kk * 256 + c];
            split2(acc, hh.s[e], ll.s[e]);
        }
        *reinterpret_cast<uint4*>(crh + j * 8) = hh.v;
        *reinterpret_cast<uint4*>(crl + j * 8) = ll.v;
    }
}

// ---------------------------------------------------------------- split-bf16 MFMA GEMM (3-term: hh + hl + lh)
// Y[p][o] = relu(bn(A[p][:] . W[o][:])), fp32-class precision.
// ASRC 0: A = (Ah,Al) bf16 planes [131072][K] pixel-major.
// ASRC 1: A = Xf fp32 x [B][512][16384] channel-major (transpose+split fused into staging).
// W: (Wh,Wl) [COUT][K] planes.
// MODE 0: (Yh,Yl) split planes.  MODE 1: Yf = out[b][o][n] fp32 via LDS transpose.  MODE 2: Yf [p_loc][COUT] fp32.
template<int K, int COUT, int MODE, int ASRC>
__global__ __launch_bounds__(256, 2)
void gemm_kernel(const u16* __restrict__ Ah, const u16* __restrict__ Al,
                 const float* __restrict__ Xf,
                 const u16* __restrict__ Wh, const u16* __restrict__ Wl,
                 const float* __restrict__ gg, const float* __restrict__ bbv,
                 const float* __restrict__ mmv, const float* __restrict__ vvv,
                 u16* __restrict__ Yh, u16* __restrict__ Yl,
                 float* __restrict__ Yf, int m_off) {
    static_assert(K % 64 == 0, "");
    constexpr int NT = K / 64;
    __shared__ u16 lds[4][128 * 64];         // planes: 0=Ah 1=Al 2=Wh 3=Wl; 64 KiB, XOR chunk-swizzled
    const int t = threadIdx.x;
    const int l = t & 63;
    const int w = t >> 6;
    const int wr = w >> 1, wc = w & 1;
    const int l15 = l & 15, l4 = l >> 4;
    const int o0 = blockIdx.x * 128;         // o fastest-varying -> A-tile L2 reuse across o-blocks
    const int m_loc = blockIdx.y * 128;
    const int m_glob = m_off + m_loc;
    const int bb = m_glob >> 14;             // 128 | 16384 -> tiles never straddle batch
    const int nb = m_glob & 16383;

    f32x4 acc[4][4];
#pragma unroll
    for (int mi = 0; mi < 4; ++mi)
#pragma unroll
        for (int ni = 0; ni < 4; ++ni) acc[mi][ni] = f32x4{0.f, 0.f, 0.f, 0.f};

    uint4 rah[4], ral[4], rbh[4], rbl[4];
    float fa[4][8];

    auto stage_load = [&](int kt) {
        if constexpr (ASRC == 0) {
#pragma unroll
            for (int i = 0; i < 4; ++i) {
                int cidx = t + 256 * i, row = cidx >> 3, cg = cidx & 7;
                size_t off = (size_t)(m_glob + row) * K + kt * 64 + cg * 8;
                rah[i] = *reinterpret_cast<const uint4*>(Ah + off);
                ral[i] = *reinterpret_cast<const uint4*>(Al + off);
            }
        } else {
#pragma unroll
            for (int i = 0; i < 4; ++i) {
                int task = t + 256 * i;
                int n = task & 127, oct = task >> 7;
                const float* src = Xf + (((size_t)bb * 512 + kt * 64 + oct * 8) << 14) + nb + n;
#pragma unroll
                for (int e = 0; e < 8; ++e) fa[i][e] = src[(size_t)e << 14];
            }
        }
#pragma unroll
        for (int i = 0; i < 4; ++i) {
            int cidx = t + 256 * i, row = cidx >> 3, cg = cidx & 7;
            size_t off = (size_t)(o0 + row) * K + kt * 64 + cg * 8;
            rbh[i] = *reinterpret_cast<const uint4*>(Wh + off);
            rbl[i] = *reinterpret_cast<const uint4*>(Wl + off);
        }
    };
    auto stage_write = [&]() {
        if constexpr (ASRC == 0) {
#pragma unroll
            for (int i = 0; i < 4; ++i) {
                int cidx = t + 256 * i, row = cidx >> 3, cg = cidx & 7;
                int sc = row * 64 + ((cg ^ (row & 7)) * 8);
                *reinterpret_cast<uint4*>(&lds[0][sc]) = rah[i];
                *reinterpret_cast<uint4*>(&lds[1][sc]) = ral[i];
            }
        } else {
#pragma unroll
            for (int i = 0; i < 4; ++i) {
                int task = t + 256 * i;
                int n = task & 127, oct = task >> 7;
                U4 ph, plo;
#pragma unroll
                for (int e = 0; e < 8; ++e) split2(fa[i][e], ph.s[e], plo.s[e]);
                int sc = n * 64 + ((oct ^ (n & 7)) * 8);
                *reinterpret_cast<uint4*>(&lds[0][sc]) = ph.v;
                *reinterpret_cast<uint4*>(&lds[1][sc]) = plo.v;
            }
        }
#pragma unroll
        for (int i = 0; i < 4; ++i) {
            int cidx = t + 256 * i, row = cidx >> 3, cg = cidx & 7;
            int sc = row * 64 + ((cg ^ (row & 7)) * 8);
            *reinterpret_cast<uint4*>(&lds[2][sc]) = rbh[i];
            *reinterpret_cast<uint4*>(&lds[3][sc]) = rbl[i];
        }
    };

    stage_load(0);
    stage_write();
    __syncthreads();

    for (int kt = 0; kt < NT; ++kt) {
        const bool more = (kt + 1 < NT);
        if (more) stage_load(kt + 1);        // issue next-tile globals under MFMA
#pragma unroll
        for (int kk = 0; kk < 2; ++kk) {
            bf16x8 ah[4], al[4], bh[4], bl[4];
#pragma unroll
            for (int mi = 0; mi < 4; ++mi) {
                int row = wr * 64 + mi * 16 + l15;
                int idx = row * 64 + (((kk * 4 + l4) ^ (row & 7)) * 8);
                ah[mi] = *reinterpret_cast<const bf16x8*>(&lds[0][idx]);
                al[mi] = *reinterpret_cast<const bf16x8*>(&lds[1][idx]);
            }
#pragma unroll
            for (int ni = 0; ni < 4; ++ni) {
                int row = wc * 64 + ni * 16 + l15;
                int idx = row * 64 + (((kk * 4 + l4) ^ (row & 7)) * 8);
                bh[ni] = *reinterpret_cast<const bf16x8*>(&lds[2][idx]);
                bl[ni] = *reinterpret_cast<const bf16x8*>(&lds[3][idx]);
            }
#pragma unroll
            for (int mi = 0; mi < 4; ++mi)
#pragma unroll
                for (int ni = 0; ni < 4; ++ni) {
                    acc[mi][ni] = __builtin_amdgcn_mfma_f32_16x16x32_bf16(ah[mi], bh[ni], acc[mi][ni], 0, 0, 0);
                    acc[mi][ni] = __builtin_amdgcn_mfma_f32_16x16x32_bf16(ah[mi], bl[ni], acc[mi][ni], 0, 0, 0);
                    acc[mi][ni] = __builtin_amdgcn_mfma_f32_16x16x32_bf16(al[mi], bh[ni], acc[mi][ni], 0, 0, 0);
                }
        }
        __syncthreads();                      // all reads of buffer done
        if (more) { stage_write(); __syncthreads(); }
    }

    if constexpr (MODE == 0) {
#pragma unroll
        for (int ni = 0; ni < 4; ++ni) {
            int o = o0 + wc * 64 + ni * 16 + l15;
            float scl = gg[o] * __frsqrt_rn(vvv[o] + 1e-5f);
            float shf = bbv[o] - mmv[o] * scl;
#pragma unroll
            for (int mi = 0; mi < 4; ++mi) {
                int pr = m_glob + wr * 64 + mi * 16 + l4 * 4;
#pragma unroll
                for (int r = 0; r < 4; ++r) {
                    float y = fmaxf(acc[mi][ni][r] * scl + shf, 0.f);
                    u16 h, lo2; split2(y, h, lo2);
                    Yh[(size_t)(pr + r) * COUT + o] = h;
                    Yl[(size_t)(pr + r) * COUT + o] = lo2;
                }
            }
        }
    } else if constexpr (MODE == 2) {
#pragma unroll
        for (int ni = 0; ni < 4; ++ni) {
            int o = o0 + wc * 64 + ni * 16 + l15;
            float scl = gg[o] * __frsqrt_rn(vvv[o] + 1e-5f);
            float shf = bbv[o] - mmv[o] * scl;
#pragma unroll
            for (int mi = 0; mi < 4; ++mi) {
                int pr = m_loc + wr * 64 + mi * 16 + l4 * 4;   // pass-local rows
#pragma unroll
                for (int r = 0; r < 4; ++r) {
                    float y = fmaxf(acc[mi][ni][r] * scl + shf, 0.f);
                    Yf[(size_t)(pr + r) * COUT + o] = y;
                }
            }
        }
    } else {
        // final: out[b][o][n] fp32, coalesced via LDS transpose [64][132]
        float* ldsf = reinterpret_cast<float*>(&lds[0][0]);
#pragma unroll 1
        for (int pass = 0; pass < 2; ++pass) {
            __syncthreads();
#pragma unroll
            for (int nj = 0; nj < 2; ++nj) {
                int ni = pass * 2 + nj;
                int o = o0 + wc * 64 + ni * 16 + l15;
                float scl = gg[o] * __frsqrt_rn(vvv[o] + 1e-5f);
                float shf = bbv[o] - mmv[o] * scl;
                int lrow = wc * 32 + nj * 16 + l15;
                int lcolb = wr * 64 + l4 * 4;
#pragma unroll
                for (int mi = 0; mi < 4; ++mi)
#pragma unroll
                    for (int r = 0; r < 4; ++r) {
                        float y = fmaxf(acc[mi][ni][r] * scl + shf, 0.f);
                        ldsf[lrow * 132 + lcolb + mi * 16 + r] = y;
                    }
            }
            __syncthreads();
#pragma unroll
            for (int j = 0; j < 32; ++j) {
                int idx = j * 256 + t;
                int row = idx >> 7, col = idx & 127;
                int o = o0 + (row >> 5) * 64 + pass * 32 + (row & 31);
                Yf[(size_t)bb * (512 * 16384) + (size_t)o * 16384 + nb + col] = ldsf[row * 132 + col];
            }
        }
    }
}

// ---------------------------------------------------------------- launch
extern "C" void kernel_launch(void* const* d_in, const int* in_sizes, int n_in,
                              void* d_out, int out_size, void* d_ws, size_t ws_size,
                              hipStream_t stream) {
    const float* x     = (const float*)d_in[0];
    const float* proxy = (const float*)d_in[1];
    const float* pw1 = (const float*)d_in[2];
    const float* pg1 = (const float*)d_in[3];
    const float* pb1 = (const float*)d_in[4];
    const float* pm1 = (const float*)d_in[5];
    const float* pv1 = (const float*)d_in[6];
    const float* pw2 = (const float*)d_in[7];
    const float* pg2 = (const float*)d_in[8];
    const float* pb2 = (const float*)d_in[9];
    const float* pm2 = (const float*)d_in[10];
    const float* pv2 = (const float*)d_in[11];
    const float* ow1 = (const float*)d_in[12];
    const float* og1 = (const float*)d_in[13];
    const float* ob1 = (const float*)d_in[14];
    const float* om1 = (const float*)d_in[15];
    const float* ov1 = (const float*)d_in[16];
    const float* ow2 = (const float*)d_in[17];
    const float* og2 = (const float*)d_in[18];
    const float* ob2 = (const float*)d_in[19];
    const float* om2 = (const float*)d_in[20];
    const float* ov2 = (const float*)d_in[21];
    const float* dw  = (const float*)d_in[22];
    const float* dg  = (const float*)d_in[23];
    const float* db  = (const float*)d_in[24];
    const float* dm  = (const float*)d_in[25];
    const float* dv  = (const float*)d_in[26];
    const float* uw  = (const float*)d_in[27];
    const float* ug  = (const float*)d_in[28];
    const float* ub  = (const float*)d_in[29];
    const float* um  = (const float*)d_in[30];
    const float* uv  = (const float*)d_in[31];

    char* ws = (char*)d_ws;
    // small region first (fixed offsets)
    u16* wpw1h = (u16*)(ws + 0);               // 262144 B
    u16* wpw1l = (u16*)(ws + 262144);
    u16* wpw2h = (u16*)(ws + 524288);          // 131072 B
    u16* wpw2l = (u16*)(ws + 655360);
    u16* wuwh  = (u16*)(ws + 786432);          // 262144 B
    u16* wuwl  = (u16*)(ws + 1048576);
    float* kmat = (float*)(ws + 1310720);      // 155648 B
    float* vmat = (float*)(ws + 1466368);      // 155648 B -> ends 1622016
    u16* q1h = (u16*)(ws + 1703936);           // 67108864 B
    u16* q1l = (u16*)(ws + 68812800);          // 67108864 B -> ends 135921664
    float* q2f = (float*)(ws + 135921664ull);  // 134217728/passes B
    u16* ctxh = q1h;                           // pass-disjoint alias (ctx rows < pass clobber only consumed q1 rows)
    u16* ctxl = q1l;

    // pick minimal pass count whose q2 chunk fits the workspace
    int passes = 1;
    while (passes < 16 && 135921664ull + 134217728ull / (size_t)passes > ws_size) passes <<= 1;

    convert_split_kernel<<<512, 256, 0, stream>>>(pw1, wpw1h, wpw1l, 131072);
    convert_split_kernel<<<256, 256, 0, stream>>>(pw2, wpw2h, wpw2l, 65536);
    convert_split_kernel<<<512, 256, 0, stream>>>(uw,  wuwh,  wuwl,  131072);

    KVArgs ka{proxy, ow1, og1, ob1, om1, ov1, ow2, og2, ob2, om2, ov2,
              dw, dg, db, dm, dv, kmat, vmat};
    kv_kernel<<<8, 256, 0, stream>>>(ka);

    // gemm1: x (fp32, fused transpose+split) -> q1 (hi/lo), K=512
    gemm_kernel<512, 256, 0, 1><<<dim3(2, 1024), 256, 0, stream>>>(
        nullptr, nullptr, x, wpw1h, wpw1l, pg1, pb1, pm1, pv1, q1h, q1l, nullptr, 0);

    const int mb = 1024 / passes;              // m-blocks per pass
    for (int p = 0; p < passes; ++p) {
        const int m_off = p * mb * 128;
        // gemm2: q1 -> q2 fp32 (pass-local buffer), K=256
        gemm_kernel<256, 256, 2, 0><<<dim3(2, mb), 256, 0, stream>>>(
            q1h, q1l, nullptr, wpw2h, wpw2l, pg2, pb2, pm2, pv2, nullptr, nullptr, q2f, m_off);
        // attention: fp32 logits/softmax, ctx -> split planes (over dead q1 rows)
        AttnArgs aa{q2f, kmat, vmat, ctxh, ctxl, (long long)m_off};
        attn_kernel<<<mb / 2, 256, 0, stream>>>(aa);
    }

    // gemm_up: ctx -> out[b][o][n] fp32, K=256, COUT=512
    gemm_kernel<256, 512, 1, 0><<<dim3(4, 1024), 256, 0, stream>>>(
        ctxh, ctxl, nullptr, wuwh, wuwl, ug, ub, um, uv, nullptr, nullptr, (float*)d_out, 0);
}